// Round 1
// 1166.645 us; speedup vs baseline: 1.2923x; 1.2923x over previous
//
#include <hip/hip_runtime.h>
#include <hip/hip_bf16.h>

#define NP_ 1500000
#define NV_ 1200000
#define S_  50000
#define E_  1600000

// ---------------- CSR build ----------------

__global__ void k_zero(int* a, int* b, int* c, int* d, int n) {
    int i = blockIdx.x * blockDim.x + threadIdx.x;
    if (i < n) { a[i] = 0; b[i] = 0; c[i] = 0; d[i] = 0; }
}

// merged histogram: points then edges in one grid
__global__ void k_hist2(const int* __restrict__ sp, int* __restrict__ pcnt,
                        const int* __restrict__ eu, int* __restrict__ ecnt) {
    int i = blockIdx.x * blockDim.x + threadIdx.x;
    if (i < NP_) {
        atomicAdd(&pcnt[sp[i]], 1);
    } else {
        int j = i - NP_;
        if (j < E_) atomicAdd(&ecnt[eu[j]], 1);
    }
}

// exclusive scan over S_ ints; block 0 -> points, block 1 -> edges
__global__ void k_scan2(const int* __restrict__ pcnt, int* __restrict__ pstart,
                        const int* __restrict__ ecnt, int* __restrict__ estart) {
    __shared__ int sums[1024];
    const int* cnt = (blockIdx.x == 0) ? pcnt : ecnt;
    int* start = (blockIdx.x == 0) ? pstart : estart;
    const int n = S_;
    int t = threadIdx.x;
    int chunk = (n + 1023) / 1024;
    int lo = t * chunk;
    int hi = lo + chunk; if (hi > n) hi = n;
    int s = 0;
    for (int i = lo; i < hi; i++) s += cnt[i];
    sums[t] = s;
    __syncthreads();
    for (int off = 1; off < 1024; off <<= 1) {
        int v = (t >= off) ? sums[t - off] : 0;
        __syncthreads();
        sums[t] += v;
        __syncthreads();
    }
    int run = sums[t] - s;  // exclusive prefix
    for (int i = lo; i < hi; i++) { start[i] = run; run += cnt[i]; }
    if (t == 1023) start[n] = run;
}

// merged fill: points fill vidx; edges fill list/evs AND compute pos inline (k_pos fused)
__global__ void k_fill2(const int* __restrict__ sp, const int* __restrict__ imap,
                        const int* __restrict__ pstart, int* __restrict__ pcur,
                        int* __restrict__ vidx,
                        const int* __restrict__ eu, const int* __restrict__ ev,
                        const int* __restrict__ estart, int* __restrict__ ecur,
                        int* __restrict__ elist, int* __restrict__ evsarr,
                        const float* __restrict__ ctr,
                        const float* __restrict__ pw1, const float* __restrict__ pb1,
                        const float* __restrict__ pw2, const float* __restrict__ pb2,
                        float* __restrict__ posv) {
    int i = blockIdx.x * blockDim.x + threadIdx.x;
    if (i < NP_) {
        int s = sp[i];
        int off = atomicAdd(&pcur[s], 1);
        vidx[pstart[s] + off] = imap[i];
    } else {
        int e = i - NP_;
        if (e < E_) {
            int u = eu[e], w = ev[e];
            int off = atomicAdd(&ecur[u], 1);
            int r = estart[u] + off;
            elist[r] = e;
            evsarr[r] = w;
            float dx = ctr[u * 3]     - ctr[w * 3];
            float dy = ctr[u * 3 + 1] - ctr[w * 3 + 1];
            float dz = ctr[u * 3 + 2] - ctr[w * 3 + 2];
            float pos = pb2[0];   // uniform -> s_load
            #pragma unroll
            for (int hh = 0; hh < 16; hh++) {
                float aa = pb1[hh] + dx * pw1[hh * 3] + dy * pw1[hh * 3 + 1] + dz * pw1[hh * 3 + 2];
                pos += fmaxf(aa, 0.0f) * pw2[hh];
            }
            posv[r] = pos;
        }
    }
}

// ---------------- point semantic head: gather + 32->32 BN ReLU ->20 ----------------
// Weights are wave-uniform: read straight from global with compile-time indices so
// they scalarize to s_load (constant cache) and feed v_fmac's SGPR operand.
// No LDS, no h[32] buffer (second matmul fused into j loop) -> fits in registers.

__global__ __launch_bounds__(256, 4) void k_point_head(
    const float* __restrict__ feats, const int* __restrict__ imap,
    const float* __restrict__ W1, const float* __restrict__ b1,
    const float* __restrict__ g, const float* __restrict__ be,
    const float* __restrict__ W2, const float* __restrict__ b2,
    float* __restrict__ out, int n)
{
    int p = blockIdx.x * 256 + threadIdx.x;
    if (p >= n) return;
    const float4* src = (const float4*)(feats + (size_t)imap[p] * 32);
    float x[32];
    #pragma unroll
    for (int i = 0; i < 8; i++) {
        float4 t = src[i];
        x[i * 4] = t.x; x[i * 4 + 1] = t.y; x[i * 4 + 2] = t.z; x[i * 4 + 3] = t.w;
    }
    float o[20];
    #pragma unroll
    for (int c = 0; c < 20; c++) o[c] = b2[c];
    #pragma unroll
    for (int j = 0; j < 32; j++) {
        float a = b1[j];
        #pragma unroll
        for (int i = 0; i < 32; i++) a = fmaf(x[i], W1[j * 32 + i], a);
        a = a * (g[j] * 0.9999500037f) + be[j];   // g*rsqrt(1.0001) folded on SALU
        a = fmaxf(a, 0.0f);
        #pragma unroll
        for (int c = 0; c < 20; c++) o[c] = fmaf(a, W2[c * 32 + j], o[c]);
    }
    float4* dst = (float4*)(out + (size_t)p * 20);
    #pragma unroll
    for (int i = 0; i < 5; i++) {
        float4 o4;
        o4.x = o[i * 4]; o4.y = o[i * 4 + 1]; o4.z = o[i * 4 + 2]; o4.w = o[i * 4 + 3];
        dst[i] = o4;
    }
}

// ---------------- segment mean via CSR (half-wave = 32 dims per superpoint) ----------------

__global__ __launch_bounds__(256) void k_mean(
    const float* __restrict__ feats, const int* __restrict__ vidx,
    const int* __restrict__ start, float* __restrict__ emb)
{
    int t = blockIdx.x * 256 + threadIdx.x;
    int s = t >> 5, d = t & 31;
    if (s >= S_) return;
    int beg = start[s], end = start[s + 1];
    float acc = 0.0f;
    int i = beg;
    for (; i + 4 <= end; i += 4) {
        int p0 = vidx[i], p1 = vidx[i + 1], p2 = vidx[i + 2], p3 = vidx[i + 3];
        float f0 = feats[(size_t)p0 * 32 + d];
        float f1 = feats[(size_t)p1 * 32 + d];
        float f2 = feats[(size_t)p2 * 32 + d];
        float f3 = feats[(size_t)p3 * 32 + d];
        acc += f0 + f1 + f2 + f3;
    }
    for (; i < end; i++) acc += feats[(size_t)vidx[i] * 32 + d];
    float c = (float)(end - beg);
    emb[(size_t)s * 32 + d] = acc / fmaxf(c, 1.0f);
}

// ---------------- ecc = emb @ W_ecc.T  (persistent blocks, stage weights once) ----------------

__global__ __launch_bounds__(256) void k_ecc(
    const float* __restrict__ emb, const float* __restrict__ Wecc, float* __restrict__ ecc)
{
    __shared__ float WL[64 * 33];
    int tid = threadIdx.x;
    for (int idx = tid; idx < 64 * 32; idx += 256) WL[(idx >> 5) * 33 + (idx & 31)] = Wecc[idx];
    __syncthreads();
    int w = tid >> 6, j = tid & 63;
    for (int s0 = blockIdx.x * 4 + w; s0 < S_; s0 += gridDim.x * 4) {
        int s = __builtin_amdgcn_readfirstlane(s0);   // uniform -> x loads become s_load
        const float* x = emb + (size_t)s * 32;
        float a = 0.0f;
        #pragma unroll
        for (int i = 0; i < 32; i++) a = fmaf(x[i], WL[j * 33 + i], a);
        ecc[(size_t)s * 64 + j] = a;
    }
}

// ---------------- q,k,v projections (persistent blocks) ----------------

__global__ __launch_bounds__(256) void k_qkv(
    const float* __restrict__ ecc,
    const float* __restrict__ Wq, const float* __restrict__ Wk, const float* __restrict__ Wv,
    float* __restrict__ q, float* __restrict__ k, float* __restrict__ v)
{
    __shared__ float QL[64 * 65], KL[64 * 65], VL[64 * 65];
    int tid = threadIdx.x;
    for (int idx = tid; idx < 4096; idx += 256) {
        int r = idx >> 6, c = idx & 63;
        QL[r * 65 + c] = Wq[idx]; KL[r * 65 + c] = Wk[idx]; VL[r * 65 + c] = Wv[idx];
    }
    __syncthreads();
    int w = tid >> 6, j = tid & 63;
    for (int s0 = blockIdx.x * 4 + w; s0 < S_; s0 += gridDim.x * 4) {
        int s = __builtin_amdgcn_readfirstlane(s0);
        const float* x = ecc + (size_t)s * 64;
        float aq = 0.0f, ak = 0.0f, av = 0.0f;
        #pragma unroll
        for (int i = 0; i < 64; i++) {
            float xi = x[i];
            aq = fmaf(xi, QL[j * 65 + i], aq);
            ak = fmaf(xi, KL[j * 65 + i], ak);
            av = fmaf(xi, VL[j * 65 + i], av);
        }
        q[(size_t)s * 64 + j] = aq;
        k[(size_t)s * 64 + j] = ak;
        v[(size_t)s * 64 + j] = av;
    }
}

// ---------------- generic 64->64 BN ReLU -> C head (persistent blocks) ----------------

__global__ __launch_bounds__(256) void k_head(
    const float* __restrict__ in,
    const float* __restrict__ W1, const float* __restrict__ b1,
    const float* __restrict__ g, const float* __restrict__ be,
    const float* __restrict__ W2, const float* __restrict__ b2,
    float* __restrict__ out, int C)
{
    __shared__ float W1L[64 * 65];
    __shared__ float W2L[20 * 65];
    __shared__ float b1L[64], sL[64], beL[64], b2L[20];
    __shared__ float hbuf[4][64];
    int tid = threadIdx.x;
    for (int idx = tid; idx < 4096; idx += 256) W1L[(idx >> 6) * 65 + (idx & 63)] = W1[idx];
    for (int idx = tid; idx < C * 64; idx += 256) W2L[(idx >> 6) * 65 + (idx & 63)] = W2[idx];
    if (tid < 64) { b1L[tid] = b1[tid]; sL[tid] = g[tid] * 0.9999500037f; beL[tid] = be[tid]; }
    if (tid < C) b2L[tid] = b2[tid];
    __syncthreads();
    int w = tid >> 6, lane = tid & 63;
    // hbuf[w] is wave-private: no __syncthreads needed inside the loop
    for (int s0 = blockIdx.x * 4 + w; s0 < S_; s0 += gridDim.x * 4) {
        int s = __builtin_amdgcn_readfirstlane(s0);
        const float* x = in + (size_t)s * 64;
        float a = b1L[lane];
        #pragma unroll
        for (int i = 0; i < 64; i++) a = fmaf(x[i], W1L[lane * 65 + i], a);
        a = a * sL[lane] + beL[lane];
        float h = fmaxf(a, 0.0f);
        hbuf[w][lane] = h;
        if (lane < C) {
            float acc = b2L[lane];
            #pragma unroll
            for (int j = 0; j < 64; j++) acc = fmaf(hbuf[w][j], W2L[lane * 65 + j], acc);
            out[(size_t)s * C + lane] = acc;
        }
    }
}

// ---------------- fused: aff + softmax + weighted v scatter (8 edges in flight) ----------------

__global__ __launch_bounds__(256) void k_attn(
    const int* __restrict__ start, const int* __restrict__ list,
    const int* __restrict__ evs, const float* __restrict__ posv,
    const float* __restrict__ q, const float* __restrict__ k,
    const float* __restrict__ v, const float* __restrict__ ecc,
    float* __restrict__ affs, float* __restrict__ soft, float* __restrict__ featb)
{
    int t = blockIdx.x * 256 + threadIdx.x;
    int s0 = t >> 6, lane = t & 63;
    if (s0 >= S_) return;
    int s = __builtin_amdgcn_readfirstlane(s0);  // uniform: evs/posv/affs loops scalarize
    int beg = start[s], end = start[s + 1];
    float qv = q[(size_t)s * 64 + lane];

    // pass 1: dot products (8 edges in flight), aff in CSR order, running max
    float m = -3.0e38f;
    int r = beg;
    for (; r + 8 <= end; r += 8) {
        float p[8];
        #pragma unroll
        for (int u = 0; u < 8; u++) p[u] = qv * k[(size_t)evs[r + u] * 64 + lane];
        #pragma unroll
        for (int o = 32; o; o >>= 1) {
            #pragma unroll
            for (int u = 0; u < 8; u++) p[u] += __shfl_xor(p[u], o, 64);
        }
        float a[8];
        #pragma unroll
        for (int u = 0; u < 8; u++) { a[u] = p[u] * 0.125f * posv[r + u]; m = fmaxf(m, a[u]); }
        float av = a[0];
        #pragma unroll
        for (int u = 1; u < 8; u++) av = (lane == u) ? a[u] : av;
        if (lane < 8) affs[r + lane] = av;
    }
    for (; r < end; r++) {
        float p = qv * k[(size_t)evs[r] * 64 + lane];
        #pragma unroll
        for (int o = 32; o; o >>= 1) p += __shfl_xor(p, o, 64);
        float a = p * 0.125f * posv[r];
        m = fmaxf(m, a);
        if (lane == 0) affs[r] = a;
    }
    // m is wave-uniform

    // pass 2: sum of exp (coalesced strided read)
    float tot = 0.0f;
    for (int i = beg + lane; i < end; i += 64) tot += __expf(affs[i] - m);
    #pragma unroll
    for (int o = 32; o; o >>= 1) tot += __shfl_xor(tot, o, 64);
    float inv = tot > 0.0f ? 1.0f / tot : 0.0f;

    // pass 3: weighted v gather (8 in flight), soft scatter to original edge order
    float r0 = 0.0f, r1 = 0.0f, r2 = 0.0f, r3 = 0.0f;
    int i = beg;
    for (; i + 8 <= end; i += 8) {
        float sv[8];
        #pragma unroll
        for (int u = 0; u < 8; u++) sv[u] = __expf(affs[i + u] - m) * inv;
        float vv[8];
        #pragma unroll
        for (int u = 0; u < 8; u++) vv[u] = v[(size_t)evs[i + u] * 64 + lane];
        r0 = fmaf(sv[0], vv[0], r0); r1 = fmaf(sv[1], vv[1], r1);
        r2 = fmaf(sv[2], vv[2], r2); r3 = fmaf(sv[3], vv[3], r3);
        r0 = fmaf(sv[4], vv[4], r0); r1 = fmaf(sv[5], vv[5], r1);
        r2 = fmaf(sv[6], vv[6], r2); r3 = fmaf(sv[7], vv[7], r3);
        float ssel = sv[0];
        #pragma unroll
        for (int u = 1; u < 8; u++) ssel = (lane == u) ? sv[u] : ssel;
        if (lane < 8) soft[list[i + lane]] = ssel;
    }
    for (; i < end; i++) {
        float sf = __expf(affs[i] - m) * inv;
        r0 = fmaf(sf, v[(size_t)evs[i] * 64 + lane], r0);
        if (lane == 0) soft[list[i]] = sf;
    }
    float res = (r0 + r1) + (r2 + r3);
    featb[(size_t)s * 64 + lane] = ecc[(size_t)s * 64 + lane] + res;
}

// ---------------- launch ----------------

extern "C" void kernel_launch(void* const* d_in, const int* in_sizes, int n_in,
                              void* d_out, int out_size, void* d_ws, size_t ws_size,
                              hipStream_t stream) {
    const float* output_feats = (const float*)d_in[0];
    const int*   input_map    = (const int*)d_in[1];
    const int*   superpoint   = (const int*)d_in[2];
    const float* ctr          = (const float*)d_in[3];
    const int*   edge_u       = (const int*)d_in[4];
    const int*   edge_v       = (const int*)d_in[5];
    const float* W_ecc        = (const float*)d_in[6];
    const float* lin_W1 = (const float*)d_in[7];
    const float* lin_b1 = (const float*)d_in[8];
    const float* lin_g  = (const float*)d_in[9];
    const float* lin_be = (const float*)d_in[10];
    const float* lin_W2 = (const float*)d_in[11];
    const float* lin_b2 = (const float*)d_in[12];
    const float* pos_W1 = (const float*)d_in[43];
    const float* pos_b1 = (const float*)d_in[44];
    const float* pos_W2 = (const float*)d_in[45];
    const float* pos_b2 = (const float*)d_in[46];
    const float* Wq     = (const float*)d_in[47];
    const float* Wk     = (const float*)d_in[48];
    const float* Wv     = (const float*)d_in[49];

    float* out = (float*)d_out;
    float* o_sem    = out;                    // [NP,20]
    float* o_spsem  = out + 30000000;         // [S,20]
    float* o_spoff  = out + 31000000;         // [S,3]
    float* o_spocc  = out + 31150000;         // [S]
    float* o_spsize = out + 31200000;         // [S]
    float* o_soft   = out + 31250000;         // [E]
    float* o_spdisc = out + 32850000;         // [S,7]

    // workspace layout
    char* base = (char*)d_ws;
    size_t off = 0;
    auto alloc = [&](size_t bytes) -> char* {
        char* p = base + off;
        off = (off + bytes + 255) & ~(size_t)255;
        return p;
    };
    int*   pt_cnt   = (int*)alloc(S_ * 4);
    int*   pt_start = (int*)alloc((S_ + 1) * 4);
    int*   pt_cur   = (int*)alloc(S_ * 4);
    int*   vidx     = (int*)alloc((size_t)NP_ * 4);
    int*   e_cnt    = (int*)alloc(S_ * 4);
    int*   e_start  = (int*)alloc((S_ + 1) * 4);
    int*   e_cur    = (int*)alloc(S_ * 4);
    int*   e_list   = (int*)alloc((size_t)E_ * 4);
    int*   e_vs     = (int*)alloc((size_t)E_ * 4);
    float* affs     = (float*)alloc((size_t)E_ * 4);
    float* posv     = (float*)alloc((size_t)E_ * 4);
    float* emb      = (float*)alloc((size_t)S_ * 32 * 4);
    float* ecc      = (float*)alloc((size_t)S_ * 64 * 4);
    float* qb       = (float*)alloc((size_t)S_ * 64 * 4);
    float* kb       = (float*)alloc((size_t)S_ * 64 * 4);
    float* vb       = (float*)alloc((size_t)S_ * 64 * 4);
    float* featb    = qb;  // safe overlay: wave s reads q-row s before writing featb-row s

    const int NTOT = NP_ + E_;   // merged hist/fill grids

    k_zero<<<(S_ + 255) / 256, 256, 0, stream>>>(pt_cnt, pt_cur, e_cnt, e_cur, S_);
    k_hist2<<<(NTOT + 255) / 256, 256, 0, stream>>>(superpoint, pt_cnt, edge_u, e_cnt);
    k_scan2<<<2, 1024, 0, stream>>>(pt_cnt, pt_start, e_cnt, e_start);
    k_fill2<<<(NTOT + 255) / 256, 256, 0, stream>>>(
        superpoint, input_map, pt_start, pt_cur, vidx,
        edge_u, edge_v, e_start, e_cur, e_list, e_vs,
        ctr, pos_W1, pos_b1, pos_W2, pos_b2, posv);
    k_point_head<<<(NP_ + 255) / 256, 256, 0, stream>>>(
        output_feats, input_map, lin_W1, lin_b1, lin_g, lin_be, lin_W2, lin_b2, o_sem, NP_);
    k_mean<<<(S_ * 32) / 256, 256, 0, stream>>>(output_feats, vidx, pt_start, emb);
    k_ecc<<<1024, 256, 0, stream>>>(emb, W_ecc, ecc);
    k_qkv<<<768, 256, 0, stream>>>(ecc, Wq, Wk, Wv, qb, kb, vb);
    k_head<<<1024, 256, 0, stream>>>(ecc, (const float*)d_in[13], (const float*)d_in[14],
        (const float*)d_in[15], (const float*)d_in[16], (const float*)d_in[17], (const float*)d_in[18],
        o_spsem, 20);
    k_head<<<1024, 256, 0, stream>>>(ecc, (const float*)d_in[19], (const float*)d_in[20],
        (const float*)d_in[21], (const float*)d_in[22], (const float*)d_in[23], (const float*)d_in[24],
        o_spoff, 3);
    k_head<<<1024, 256, 0, stream>>>(ecc, (const float*)d_in[25], (const float*)d_in[26],
        (const float*)d_in[27], (const float*)d_in[28], (const float*)d_in[29], (const float*)d_in[30],
        o_spocc, 1);
    k_head<<<1024, 256, 0, stream>>>(ecc, (const float*)d_in[31], (const float*)d_in[32],
        (const float*)d_in[33], (const float*)d_in[34], (const float*)d_in[35], (const float*)d_in[36],
        o_spsize, 1);
    k_attn<<<S_ / 4, 256, 0, stream>>>(e_start, e_list, e_vs, posv, qb, kb, vb, ecc,
        affs, o_soft, featb);
    k_head<<<1024, 256, 0, stream>>>(featb, (const float*)d_in[37], (const float*)d_in[38],
        (const float*)d_in[39], (const float*)d_in[40], (const float*)d_in[41], (const float*)d_in[42],
        o_spdisc, 7);
}